// Round 10
// baseline (179.730 us; speedup 1.0000x reference)
//
#include <hip/hip_runtime.h>
#include <hip/hip_bf16.h>

#define BB 8
#define SS 4096
#define DD 1024
#define NN 64
#define ROWS (BB * SS)          // 32768
#define GLD 256                 // 4 gates * 64
#define NCHUNK 256              // chunks per sequence
#define CLEN 16                 // steps per chunk (NCHUNK*CLEN == SS)

typedef _Float16 f16;
using f16x8 = __attribute__((ext_vector_type(8))) _Float16;
using f16x4 = __attribute__((ext_vector_type(4))) _Float16;
using f32x4 = __attribute__((ext_vector_type(4))) float;

// ---------------- prep A: W' = ln_w ⊙ W packed fragment-linear fp16 sub-slices; Wp -> fp16 ----------------
// sub-slice s (16 KB): [cb(16)][lane(64)][8] ; element = W'[cb*16+(l&15)][s*32+(l>>4)*8+e]
__global__ void prep_pack(const float* __restrict__ Wi, const float* __restrict__ Wf,
                          const float* __restrict__ Wz, const float* __restrict__ Wo,
                          const float* __restrict__ Wp, const float* __restrict__ ln_w,
                          f16* __restrict__ Wpk, f16* __restrict__ Wpf) {
    int i = blockIdx.x * 256 + threadIdx.x;
    if (i < 32768) {
        int l = i & 63, cb = (i >> 6) & 15, s = i >> 10;
        int r = cb * 16 + (l & 15);
        int c = s * 32 + (l >> 4) * 8;
        int g = r >> 6, rem = r & 63;
        const float* W = (g == 0) ? Wi : (g == 1) ? Wf : (g == 2) ? Wz : Wo;
        const float* src = W + rem * 1024 + c;
        const float* lwp = ln_w + c;
        f16x8 v;
        #pragma unroll
        for (int e = 0; e < 8; ++e) v[e] = (f16)(src[e] * lwp[e]);
        *reinterpret_cast<f16x8*>(Wpk + (size_t)s * 8192 + cb * 512 + l * 8) = v;
    } else if (i < 32768 + 65536) {
        int j = i - 32768;
        Wpf[j] = (f16)Wp[j];
    }
}

// ---------------- prep B: ball[c] = bias_c + Σ ln_b[k] W[c,k];  e_all[c] = Σ ln_w[k] W[c,k] ----------------
__global__ __launch_bounds__(256) void prep_bias(const float* __restrict__ Wi, const float* __restrict__ bi,
                                                 const float* __restrict__ Wf, const float* __restrict__ bfv,
                                                 const float* __restrict__ Wz, const float* __restrict__ bz,
                                                 const float* __restrict__ Wo, const float* __restrict__ bo,
                                                 const float* __restrict__ ln_w, const float* __restrict__ ln_b,
                                                 float* __restrict__ ball, float* __restrict__ e_all) {
    int j = blockIdx.x * 4 + (threadIdx.x >> 6);
    int lane = threadIdx.x & 63;
    int g = j >> 6, rem = j & 63;
    const float* W  = (g == 0) ? Wi : (g == 1) ? Wf : (g == 2) ? Wz : Wo;
    const float* bs = (g == 0) ? bi : (g == 1) ? bfv : (g == 2) ? bz : bo;
    const float* row = W + rem * 1024;
    float d = 0.0f, e = 0.0f;
    #pragma unroll
    for (int t = 0; t < 16; ++t) {
        int k = lane + 64 * t;
        float w = row[k];
        e += ln_w[k] * w;
        d += ln_b[k] * w;
    }
    #pragma unroll
    for (int off = 1; off < 64; off <<= 1) {
        e += __shfl_xor(e, off);
        d += __shfl_xor(d, off);
    }
    if (lane == 0) { ball[j] = bs[rem] + d; e_all[j] = e; }
}

// ---------------- fused LN + gate GEMM: raw-barrier pipeline, coalesced staging ----------------
// 256 thr = 4 waves (wn = gate). Tile 64 x 256, BK=32, 32 steps. Grid 512 = 2 blocks/CU.
// x + W reg-staged 2 steps ahead; barriers = lgkmcnt(0)+s_barrier (NO vmcnt drain).
__global__ __launch_bounds__(256, 3) void gate_gemm(const float* __restrict__ x,
                                                    const f16* __restrict__ Wpk,
                                                    const float* __restrict__ ball,
                                                    const float* __restrict__ e_all,
                                                    float* __restrict__ gates) {
    int bm = blockIdx.x * 64;
    int tid = threadIdx.x;
    int wn = tid >> 6, lane = tid & 63;      // wn == gate index
    int lrow = lane & 15, lkg = lane >> 4;

    __shared__ __align__(16) char Wlds[2][16384];   // 16 KB per buf
    __shared__ __align__(16) char Xlds[2][4096];    // 64 rows x 64 B, slot^(row&3) swizzle
    __shared__ float2 stats_lds[64];

    // x staging: flat float4 index f = tid + 256*i over the 64x32 slice -> 16-line coalesced
    int xr0 = tid >> 3;          // rows xr0 (i=0) and xr0+32 (i=1)
    int xc4 = tid & 7;
    const float4* xsrc = reinterpret_cast<const float4*>(x) + (size_t)(bm + xr0) * 256 + xc4;
    const uint4* wsrc = reinterpret_cast<const uint4*>(Wpk) + tid;

    float4 XA0, XA1, XB0, XB1;
    uint4 WA0, WA1, WA2, WA3, WB0, WB1, WB2, WB3;

    auto loadXA = [&](int s) { XA0 = xsrc[s * 8]; XA1 = xsrc[s * 8 + 32 * 256]; };
    auto loadXB = [&](int s) { XB0 = xsrc[s * 8]; XB1 = xsrc[s * 8 + 32 * 256]; };
    auto loadWA = [&](int s) { const uint4* p = wsrc + (size_t)s * 1024; WA0 = p[0]; WA1 = p[256]; WA2 = p[512]; WA3 = p[768]; };
    auto loadWB = [&](int s) { const uint4* p = wsrc + (size_t)s * 1024; WB0 = p[0]; WB1 = p[256]; WB2 = p[512]; WB3 = p[768]; };

    float sa1 = 0.0f, sa2 = 0.0f, sb1 = 0.0f, sb2 = 0.0f;
    int xsl = (((xc4 >> 1) ^ (xr0 & 3)) << 4) + (xc4 & 1) * 8;   // swizzled byte within row
    auto writeXv = [&](int buf, float4 v0, float4 v1) {
        sa1 += v0.x + v0.y + v0.z + v0.w;
        sa2 += v0.x * v0.x + v0.y * v0.y + v0.z * v0.z + v0.w * v0.w;
        sb1 += v1.x + v1.y + v1.z + v1.w;
        sb2 += v1.x * v1.x + v1.y * v1.y + v1.z * v1.z + v1.w * v1.w;
        f16x4 p0, p1;
        p0[0] = (f16)v0.x; p0[1] = (f16)v0.y; p0[2] = (f16)v0.z; p0[3] = (f16)v0.w;
        p1[0] = (f16)v1.x; p1[1] = (f16)v1.y; p1[2] = (f16)v1.z; p1[3] = (f16)v1.w;
        char* b = &Xlds[buf][0];
        *reinterpret_cast<f16x4*>(b + xr0 * 64 + xsl) = p0;
        *reinterpret_cast<f16x4*>(b + (xr0 + 32) * 64 + xsl) = p1;
    };
    auto writeWA = [&](int buf) {
        uint4* d = reinterpret_cast<uint4*>(&Wlds[buf][0]) + tid;
        d[0] = WA0; d[256] = WA1; d[512] = WA2; d[768] = WA3;
    };
    auto writeWB = [&](int buf) {
        uint4* d = reinterpret_cast<uint4*>(&Wlds[buf][0]) + tid;
        d[0] = WB0; d[256] = WB1; d[512] = WB2; d[768] = WB3;
    };

    f32x4 acc[4][4] = {};
    auto compute = [&](int buf) {
        f16x8 a[4];
        #pragma unroll
        for (int mf = 0; mf < 4; ++mf) {
            int row = mf * 16 + lrow;
            a[mf] = *reinterpret_cast<const f16x8*>(&Xlds[buf][0] + row * 64 + ((lkg ^ (row & 3)) << 4));
        }
        #pragma unroll
        for (int nf = 0; nf < 4; ++nf) {
            int cb = wn * 4 + nf;
            f16x8 w = *reinterpret_cast<const f16x8*>(&Wlds[buf][0] + cb * 1024 + lane * 16);
            #pragma unroll
            for (int mf = 0; mf < 4; ++mf)
                acc[mf][nf] = __builtin_amdgcn_mfma_f32_16x16x32_f16(a[mf], w, acc[mf][nf], 0, 0, 0);
        }
    };
    auto stepSync = [&]() {
        asm volatile("s_waitcnt lgkmcnt(0)" ::: "memory");
        __builtin_amdgcn_s_barrier();
        __builtin_amdgcn_sched_barrier(0);
    };

    // prologue: stage slice 0; slice 1 in B regs; prefetch slice 2 into A
    loadXA(0); loadWA(0);
    loadXB(1); loadWB(1);
    writeWA(0); writeXv(0, XA0, XA1);
    loadXA(2); loadWA(2);
    stepSync();

    for (int it = 0; it < 16; ++it) {
        int s = 2 * it;
        // even step: consume buf0 (slice s); stage s+1 (B) -> buf1; prefetch s+3 -> B
        compute(0);
        writeWB(1); writeXv(1, XB0, XB1);
        if (s + 3 < 32) { loadXB(s + 3); loadWB(s + 3); }
        stepSync();
        // odd step: consume buf1 (s+1); stage s+2 (A) -> buf0; prefetch s+4 -> A
        compute(1);
        if (s + 2 < 32) { writeWA(0); writeXv(0, XA0, XA1); }
        if (s + 4 < 32) { loadXA(s + 4); loadWA(s + 4); }
        stepSync();
    }

    // stats: row xr0 owned by 8 consecutive threads (xc4 0..7)
    sa1 += __shfl_xor(sa1, 1); sa2 += __shfl_xor(sa2, 1);
    sb1 += __shfl_xor(sb1, 1); sb2 += __shfl_xor(sb2, 1);
    sa1 += __shfl_xor(sa1, 2); sa2 += __shfl_xor(sa2, 2);
    sb1 += __shfl_xor(sb1, 2); sb2 += __shfl_xor(sb2, 2);
    sa1 += __shfl_xor(sa1, 4); sa2 += __shfl_xor(sa2, 4);
    sb1 += __shfl_xor(sb1, 4); sb2 += __shfl_xor(sb2, 4);
    if ((tid & 7) == 0) {
        float mu = sa1 * (1.0f / DD);
        float var = sa2 * (1.0f / DD) - mu * mu;
        float rsd = rsqrtf(var + 1e-5f);
        float2 st; st.x = mu * rsd; st.y = rsd;
        stats_lds[xr0] = st;
        mu = sb1 * (1.0f / DD);
        var = sb2 * (1.0f / DD) - mu * mu;
        rsd = rsqrtf(var + 1e-5f);
        st.x = mu * rsd; st.y = rsd;
        stats_lds[xr0 + 32] = st;
    }
    __syncthreads();

    // epilogue: LN fold + activations
    int c0 = wn * 64;
    int rb = (lane >> 4) * 4;
    #pragma unroll
    for (int mf = 0; mf < 4; ++mf) {
        #pragma unroll
        for (int nf = 0; nf < 4; ++nf) {
            int col = c0 + nf * 16 + (lane & 15);
            float bc = ball[col];
            float ec = e_all[col];
            #pragma unroll
            for (int r = 0; r < 4; ++r) {
                int rl = mf * 16 + rb + r;
                float2 st = stats_lds[rl];
                float v = acc[mf][nf][r] * st.y + bc - st.x * ec;
                float res;
                if (wn == 0 || wn == 1)      res = fminf(fmaxf(v, -20.0f), 20.0f);
                else if (wn == 2)            res = tanhf(v);
                else                         res = 1.0f / (1.0f + expf(-v));
                gates[(size_t)(bm + rl) * GLD + col] = res;
            }
        }
    }
}

// ---------------- scan phase A: per-chunk summaries -> interleaved float4 ----------------
__global__ __launch_bounds__(256) void scan_a(const float* __restrict__ gates,
                                              float4* __restrict__ s4) {
    int w = blockIdx.x * 4 + (threadIdx.x >> 6);
    int lane = threadIdx.x & 63;
    int b = w >> 8, k = w & (NCHUNK - 1);
    int t0 = k * CLEN;
    const float* gp = gates + ((size_t)(b * SS + t0)) * GLD + lane;
    float Lf = 0.0f, m = -1e30f, c = 0.0f;
    for (int t = 0; t < CLEN; ++t) {
        float li = gp[0], lf = gp[64], z = gp[128];
        gp += GLD;
        Lf += lf;
        float ma = m + lf;
        float mn = fmaxf(ma, li);
        c = expf(ma - mn) * c + expf(li - mn) * z;
        m = mn;
    }
    float4 v; v.x = Lf; v.y = m; v.z = c; v.w = 0.0f;
    s4[(size_t)(b * NCHUNK + k) * 64 + lane] = v;
}

// ---------------- scan phase B: sequential compose, prefetch-16 pipeline ----------------
__global__ __launch_bounds__(64) void scan_b(const float4* __restrict__ s4,
                                             float2* __restrict__ c2) {
    int b = blockIdx.x;
    int n = threadIdx.x;
    size_t base = (size_t)b * NCHUNK * 64 + n;
    float c = 0.0f, m = 0.0f;   // reference init: c0=0, m0=0
    float4 cur[16];
    #pragma unroll
    for (int d = 0; d < 16; ++d) cur[d] = s4[base + (size_t)d * 64];
    for (int kb = 0; kb < NCHUNK; kb += 16) {
        float4 nxt[16];
        if (kb + 16 < NCHUNK) {
            #pragma unroll
            for (int d = 0; d < 16; ++d) nxt[d] = s4[base + (size_t)(kb + 16 + d) * 64];
        }
        #pragma unroll
        for (int d = 0; d < 16; ++d) {
            float2 ci; ci.x = m; ci.y = c;
            c2[base + (size_t)(kb + d) * 64] = ci;
            float4 v = cur[d];
            float ma = m + v.x;
            float mo = fmaxf(ma, v.y);
            c = expf(ma - mo) * c + expf(v.y - mo) * v.z;
            m = mo;
        }
        #pragma unroll
        for (int d = 0; d < 16; ++d) cur[d] = nxt[d];
    }
}

// ---------------- scan phase C: replay chunks, emit h (fp16) ----------------
__global__ __launch_bounds__(256) void scan_c(const float* __restrict__ gates,
                                              const float2* __restrict__ c2,
                                              f16* __restrict__ h) {
    int w = blockIdx.x * 4 + (threadIdx.x >> 6);
    int lane = threadIdx.x & 63;
    int b = w >> 8, k = w & (NCHUNK - 1);
    int t0 = k * CLEN;
    float2 ci = c2[(size_t)(b * NCHUNK + k) * 64 + lane];
    float m = ci.x, c = ci.y;
    const float* gp = gates + ((size_t)(b * SS + t0)) * GLD + lane;
    f16* hp = h + ((size_t)(b * SS + t0)) * NN + lane;
    for (int t = 0; t < CLEN; ++t) {
        float li = gp[0], lf = gp[64], z = gp[128], o = gp[192];
        gp += GLD;
        float ma = m + lf;
        float mn = fmaxf(ma, li);
        c = expf(ma - mn) * c + expf(li - mn) * z;
        m = mn;
        *hp = (f16)(o * tanhf(c));
        hp += NN;
    }
}

// ---------------- output projection: h(32768x64) * Wpf^T(1024x64) + bp -> out ----------------
__global__ __launch_bounds__(256) void out_gemm(const f16* __restrict__ h,
                                                const f16* __restrict__ Wpf,
                                                const float* __restrict__ bp,
                                                float* __restrict__ out) {
    int tid = threadIdx.x, wid = tid >> 6, lane = tid & 63;
    int r0 = (blockIdx.x >> 1) * 32;
    int c0 = (blockIdx.x & 1) * 512 + wid * 128;
    int lrow = lane & 15, lk = (lane >> 4) * 8;

    f32x4 acc[2][8] = {};
    #pragma unroll
    for (int ks = 0; ks < 2; ++ks) {
        int kk = ks * 32;
        f16x8 a[2], bfr[8];
        #pragma unroll
        for (int mf = 0; mf < 2; ++mf)
            a[mf] = *reinterpret_cast<const f16x8*>(h + (size_t)(r0 + mf * 16 + lrow) * NN + kk + lk);
        #pragma unroll
        for (int nf = 0; nf < 8; ++nf)
            bfr[nf] = *reinterpret_cast<const f16x8*>(Wpf + (size_t)(c0 + nf * 16 + lrow) * NN + kk + lk);
        #pragma unroll
        for (int mf = 0; mf < 2; ++mf)
            #pragma unroll
            for (int nf = 0; nf < 8; ++nf)
                acc[mf][nf] = __builtin_amdgcn_mfma_f32_16x16x32_f16(a[mf], bfr[nf], acc[mf][nf], 0, 0, 0);
    }
    int rb = (lane >> 4) * 4;
    #pragma unroll
    for (int nf = 0; nf < 8; ++nf) {
        int col = c0 + nf * 16 + (lane & 15);
        float bias = bp[col];
        #pragma unroll
        for (int mf = 0; mf < 2; ++mf) {
            #pragma unroll
            for (int r = 0; r < 4; ++r) {
                int row = r0 + mf * 16 + rb + r;
                out[(size_t)row * DD + col] = acc[mf][nf][r] + bias;
            }
        }
    }
}

extern "C" void kernel_launch(void* const* d_in, const int* in_sizes, int n_in,
                              void* d_out, int out_size, void* d_ws, size_t ws_size,
                              hipStream_t stream) {
    const float* x    = (const float*)d_in[0];
    const float* ln_w = (const float*)d_in[1];
    const float* ln_b = (const float*)d_in[2];
    const float* Wi   = (const float*)d_in[3];
    const float* bi   = (const float*)d_in[4];
    const float* Wf   = (const float*)d_in[5];
    const float* bfv  = (const float*)d_in[6];
    const float* Wz   = (const float*)d_in[7];
    const float* bz   = (const float*)d_in[8];
    const float* Wo   = (const float*)d_in[9];
    const float* bo   = (const float*)d_in[10];
    const float* Wp   = (const float*)d_in[11];
    const float* bp   = (const float*)d_in[12];
    float* out = (float*)d_out;

    // gates fp32 [32768][256] at d_out floats [0, 8.39M)  (33.5 MB; dead before out_gemm)
    float* gates = (float*)d_out;
    // chunk summaries in dead d_out space (float offset 9M, 16B aligned)
    float4* s4 = (float4*)((float*)d_out + 9 * 1024 * 1024);
    float2* c2 = (float2*)((float*)d_out + 10 * 1024 * 1024);

    // Small scratch in ws (~4.9 MB)
    char* w = (char*)d_ws;
    f16* h    = (f16*)w; w += (size_t)ROWS * NN * 2;       // 4,194,304
    f16* Wpk  = (f16*)w; w += 32 * 8192 * 2;               // 524,288 (packed fp16 sub-slices)
    f16* Wpf  = (f16*)w; w += 1024 * 64 * 2;               // 131,072
    float* ball   = (float*)w;    w += 256 * 4;            // 1,024
    float* e_all  = (float*)w;    w += 256 * 4;            // 1,024

    prep_pack<<<384, 256, 0, stream>>>(Wi, Wf, Wz, Wo, Wp, ln_w, Wpk, Wpf);
    prep_bias<<<64, 256, 0, stream>>>(Wi, bi, Wf, bfv, Wz, bz, Wo, bo, ln_w, ln_b, ball, e_all);
    gate_gemm<<<ROWS / 64, 256, 0, stream>>>(x, Wpk, ball, e_all, gates);
    scan_a<<<(BB * NCHUNK) / 4, 256, 0, stream>>>(gates, s4);
    scan_b<<<BB, 64, 0, stream>>>(s4, c2);
    scan_c<<<(BB * NCHUNK) / 4, 256, 0, stream>>>(gates, c2, h);
    out_gemm<<<(ROWS / 32) * 2, 256, 0, stream>>>(h, Wpf, bp, out);
}

// Round 11
// 135.926 us; speedup vs baseline: 1.3223x; 1.3223x over previous
//
#include <hip/hip_runtime.h>
#include <hip/hip_bf16.h>

#define BB 8
#define SS 4096
#define DD 1024
#define NN 64
#define ROWS (BB * SS)          // 32768
#define GLD 256                 // 4 gates * 64
#define NCHUNK 256              // chunks per sequence
#define CLEN 16                 // steps per chunk (NCHUNK*CLEN == SS)
#define GSTRIDE 194             // padded fp32 stride for fused-scan LDS tile

typedef _Float16 f16;
using f16x8 = __attribute__((ext_vector_type(8))) _Float16;
using f32x4 = __attribute__((ext_vector_type(4))) float;

// ---------------- prep (merged): W' = ln_w ⊙ W packed fp16 sub-slices; Wp -> fp16; bias folds ----------------
// sub-slice s (16 KB): [cb(16)][lane(64)][8] ; element = W'[cb*16+(l&15)][s*32+(l>>4)*8+e]
__global__ __launch_bounds__(256) void prep_all(const float* __restrict__ Wi, const float* __restrict__ bi,
                                                const float* __restrict__ Wf, const float* __restrict__ bfv,
                                                const float* __restrict__ Wz, const float* __restrict__ bz,
                                                const float* __restrict__ Wo, const float* __restrict__ bo,
                                                const float* __restrict__ Wp,
                                                const float* __restrict__ ln_w, const float* __restrict__ ln_b,
                                                f16* __restrict__ Wpk, f16* __restrict__ Wpf,
                                                float* __restrict__ ball, float* __restrict__ e_all) {
    if (blockIdx.x < 384) {
        int i = blockIdx.x * 256 + threadIdx.x;
        if (i < 32768) {
            int l = i & 63, cb = (i >> 6) & 15, s = i >> 10;
            int r = cb * 16 + (l & 15);
            int c = s * 32 + (l >> 4) * 8;
            int g = r >> 6, rem = r & 63;
            const float* W = (g == 0) ? Wi : (g == 1) ? Wf : (g == 2) ? Wz : Wo;
            const float* src = W + rem * 1024 + c;
            const float* lwp = ln_w + c;
            f16x8 v;
            #pragma unroll
            for (int e = 0; e < 8; ++e) v[e] = (f16)(src[e] * lwp[e]);
            *reinterpret_cast<f16x8*>(Wpk + (size_t)s * 8192 + cb * 512 + l * 8) = v;
        } else if (i < 32768 + 65536) {
            int j = i - 32768;
            Wpf[j] = (f16)Wp[j];
        }
    } else {
        int j = (blockIdx.x - 384) * 4 + (threadIdx.x >> 6);
        int lane = threadIdx.x & 63;
        int g = j >> 6, rem = j & 63;
        const float* W  = (g == 0) ? Wi : (g == 1) ? Wf : (g == 2) ? Wz : Wo;
        const float* bs = (g == 0) ? bi : (g == 1) ? bfv : (g == 2) ? bz : bo;
        const float* row = W + rem * 1024;
        float d = 0.0f, e = 0.0f;
        #pragma unroll
        for (int t = 0; t < 16; ++t) {
            int k = lane + 64 * t;
            float w = row[k];
            e += ln_w[k] * w;
            d += ln_b[k] * w;
        }
        #pragma unroll
        for (int off = 1; off < 64; off <<= 1) {
            e += __shfl_xor(e, off);
            d += __shfl_xor(d, off);
        }
        if (lane == 0) { ball[j] = bs[rem] + d; e_all[j] = e; }
    }
}

// ---------------- fused LN + gate GEMM + scan phase A ----------------
// 512 thr = 8 waves (2M x 4N). Tile 128 x 256, BK=64, 16 steps. Grid 256 = 1 block/CU.
// Main loop identical to R9 (77us proven). Epilogue additionally computes the 8 per-chunk
// scan summaries (tile = 8 chunks of 16 timesteps) via LDS reuse -> s4.
__global__ __launch_bounds__(512, 1) void gate_gemm(const float* __restrict__ x,
                                                    const f16* __restrict__ Wpk,
                                                    const float* __restrict__ ball,
                                                    const float* __restrict__ e_all,
                                                    float* __restrict__ gates,
                                                    float4* __restrict__ s4) {
    int bm = blockIdx.x * 128;
    int tid = threadIdx.x;
    int wid = tid >> 6, lane = tid & 63;
    int wm = wid >> 2, wn = wid & 3;     // wn == gate index
    int lrow = lane & 15, lkg = lane >> 4;
    int srow = tid >> 2, skg = tid & 3;  // x staging: row 0..127, 16-k group

    __shared__ __align__(16) f16 Wlds[2][16384];   // 32 KB per buf (reused as glds after loop)
    __shared__ __align__(16) f16 Xlds[2][8192];    // 16 KB per buf
    __shared__ float2 stats_lds[128];

    const float4* xrow = reinterpret_cast<const float4*>(x + (size_t)(bm + srow) * DD) + skg * 4;
    float4 A0, A1, A2, A3, B0, B1, B2, B3;
    uint4 W0, W1, W2, W3;
    const uint4* wsrc = reinterpret_cast<const uint4*>(Wpk) + wid * 256 + lane;

    auto loadA = [&](int s) { const float4* p = xrow + s * 16; A0 = p[0]; A1 = p[1]; A2 = p[2]; A3 = p[3]; };
    auto loadB = [&](int s) { const float4* p = xrow + s * 16; B0 = p[0]; B1 = p[1]; B2 = p[2]; B3 = p[3]; };
    auto loadW = [&](int s) { const uint4* p = wsrc + (size_t)s * 2048; W0 = p[0]; W1 = p[64]; W2 = p[128]; W3 = p[192]; };
    auto writeW = [&](int buf) {
        uint4* d = reinterpret_cast<uint4*>((char*)&Wlds[buf][0] + wid * 4096) + lane;
        d[0] = W0; d[64] = W1; d[128] = W2; d[192] = W3;
    };

    float s1 = 0.0f, s2 = 0.0f;
    auto writeXv = [&](float4 v0, float4 v1, float4 v2, float4 v3, int buf) {
        float xv[16] = {v0.x, v0.y, v0.z, v0.w, v1.x, v1.y, v1.z, v1.w,
                        v2.x, v2.y, v2.z, v2.w, v3.x, v3.y, v3.z, v3.w};
        f16x8 p0, p1;
        #pragma unroll
        for (int e = 0; e < 8; ++e) {
            s1 += xv[e] + xv[8 + e];
            s2 += xv[e] * xv[e] + xv[8 + e] * xv[8 + e];
            p0[e] = (f16)xv[e];
            p1[e] = (f16)xv[8 + e];
        }
        char* base = (char*)&Xlds[buf][0] + srow * 128;
        int r7 = srow & 7;
        *reinterpret_cast<f16x8*>(base + 16 * ((2 * skg) ^ r7))     = p0;
        *reinterpret_cast<f16x8*>(base + 16 * ((2 * skg + 1) ^ r7)) = p1;
    };

    f32x4 acc[4][4] = {};
    auto compute = [&](int buf) {
        #pragma unroll
        for (int h = 0; h < 2; ++h) {
            f16x8 a[4];
            #pragma unroll
            for (int mf = 0; mf < 4; ++mf) {
                int row = wm * 64 + mf * 16 + lrow;
                a[mf] = *reinterpret_cast<const f16x8*>(
                    (const char*)&Xlds[buf][0] + row * 128 + 16 * ((4 * h + lkg) ^ (row & 7)));
            }
            #pragma unroll
            for (int nf = 0; nf < 4; ++nf) {
                int cb = wn * 4 + nf;
                f16x8 w = *reinterpret_cast<const f16x8*>(
                    (const char*)&Wlds[buf][0] + h * 16384 + cb * 1024 + lane * 16);
                #pragma unroll
                for (int mf = 0; mf < 4; ++mf)
                    acc[mf][nf] = __builtin_amdgcn_mfma_f32_16x16x32_f16(a[mf], w, acc[mf][nf], 0, 0, 0);
            }
        }
    };
    auto stepSync = [&]() {
        asm volatile("s_waitcnt lgkmcnt(0)" ::: "memory");
        __builtin_amdgcn_s_barrier();
        __builtin_amdgcn_sched_barrier(0);
    };

    // prologue: x(0),x(1),W(0) in regs; stage step 0; prefetch x(2), W(1)
    loadA(0); loadB(1); loadW(0);
    writeW(0);
    writeXv(A0, A1, A2, A3, 0);
    loadA(2); loadW(1);
    stepSync();

    for (int it = 0; it < 8; ++it) {
        int s = 2 * it;
        compute(0);
        writeW(1);
        writeXv(B0, B1, B2, B3, 1);
        if (s + 2 <= 15) loadW(s + 2);
        if (s + 3 <= 15) loadB(s + 3);
        stepSync();
        compute(1);
        if (s + 2 <= 15) {
            writeW(0);
            writeXv(A0, A1, A2, A3, 0);
        }
        if (s + 3 <= 15) loadW(s + 3);
        if (s + 4 <= 15) loadA(s + 4);
        stepSync();
    }

    // stats: 4 threads per row
    s1 += __shfl_xor(s1, 1); s2 += __shfl_xor(s2, 1);
    s1 += __shfl_xor(s1, 2); s2 += __shfl_xor(s2, 2);
    if ((tid & 3) == 0) {
        float mu = s1 * (1.0f / DD);
        float var = s2 * (1.0f / DD) - mu * mu;
        float rsd = rsqrtf(var + 1e-5f);
        float2 st; st.x = mu * rsd; st.y = rsd;
        stats_lds[srow] = st;
    }
    __syncthreads();

    // ---- epilogue 1: LN fold + activations -> global gates; wm==0 also stash li/lf/z to glds ----
    float* glds = reinterpret_cast<float*>(&Wlds[0][0]);   // 64 x GSTRIDE fp32 (dead Wlds)
    int c0 = wn * 64;
    int rb = (lane >> 4) * 4;
    #pragma unroll
    for (int mf = 0; mf < 4; ++mf) {
        #pragma unroll
        for (int nf = 0; nf < 4; ++nf) {
            int col = c0 + nf * 16 + (lane & 15);
            float bc = ball[col];
            float ec = e_all[col];
            #pragma unroll
            for (int r = 0; r < 4; ++r) {
                int rl = wm * 64 + mf * 16 + rb + r;
                float2 st = stats_lds[rl];
                float v = acc[mf][nf][r] * st.y + bc - st.x * ec;
                float res;
                if (wn == 0 || wn == 1)      res = fminf(fmaxf(v, -20.0f), 20.0f);
                else if (wn == 2)            res = tanhf(v);
                else                         res = 1.0f / (1.0f + expf(-v));
                gates[(size_t)(bm + rl) * GLD + col] = res;
                if (wm == 0 && wn < 3)
                    glds[(mf * 16 + rb + r) * GSTRIDE + col] = res;
            }
        }
    }
    __syncthreads();

    int b = bm >> 12;
    int cb0 = (bm & 4095) >> 4;
    auto scanChunk = [&]() {
        // wave wid scans local glds rows (wid&3)*16 .. +15, t = wid*16 + j
        int lr0 = (wid & 3) * 16;
        float Lf = 0.0f, m = -1e30f, c = 0.0f;
        #pragma unroll
        for (int j = 0; j < 16; ++j) {
            const float* g = glds + (lr0 + j) * GSTRIDE;
            float li = g[lane], lf = g[64 + lane], z = g[128 + lane];
            Lf += lf;
            float ma = m + lf;
            float mn = fmaxf(ma, li);
            c = __expf(ma - mn) * c + __expf(li - mn) * z;
            m = mn;
        }
        float4 v; v.x = Lf; v.y = m; v.z = c; v.w = 0.0f;
        s4[(size_t)(b * NCHUNK + cb0 + wid) * 64 + lane] = v;
    };

    if (wm == 0) scanChunk();     // chunks cb0..cb0+3 (rows 0-63)
    __syncthreads();

    // ---- epilogue 2: wm==1, wn<3 recompute res into glds for rows 64-127 ----
    if (wm == 1 && wn < 3) {
        #pragma unroll
        for (int mf = 0; mf < 4; ++mf) {
            #pragma unroll
            for (int nf = 0; nf < 4; ++nf) {
                int col = c0 + nf * 16 + (lane & 15);
                float bc = ball[col];
                float ec = e_all[col];
                #pragma unroll
                for (int r = 0; r < 4; ++r) {
                    int rl = 64 + mf * 16 + rb + r;
                    float2 st = stats_lds[rl];
                    float v = acc[mf][nf][r] * st.y + bc - st.x * ec;
                    float res;
                    if (wn == 0 || wn == 1)      res = fminf(fmaxf(v, -20.0f), 20.0f);
                    else                         res = tanhf(v);
                    glds[(mf * 16 + rb + r) * GSTRIDE + col] = res;
                }
            }
        }
    }
    __syncthreads();
    if (wm == 1) scanChunk();     // chunks cb0+4..cb0+7 (rows 64-127)
}

// ---------------- scan phase B: sequential compose, prefetch-16 pipeline ----------------
__global__ __launch_bounds__(64) void scan_b(const float4* __restrict__ s4,
                                             float2* __restrict__ c2) {
    int b = blockIdx.x;
    int n = threadIdx.x;
    size_t base = (size_t)b * NCHUNK * 64 + n;
    float c = 0.0f, m = 0.0f;   // reference init: c0=0, m0=0
    float4 cur[16];
    #pragma unroll
    for (int d = 0; d < 16; ++d) cur[d] = s4[base + (size_t)d * 64];
    for (int kb = 0; kb < NCHUNK; kb += 16) {
        float4 nxt[16];
        if (kb + 16 < NCHUNK) {
            #pragma unroll
            for (int d = 0; d < 16; ++d) nxt[d] = s4[base + (size_t)(kb + 16 + d) * 64];
        }
        #pragma unroll
        for (int d = 0; d < 16; ++d) {
            float2 ci; ci.x = m; ci.y = c;
            c2[base + (size_t)(kb + d) * 64] = ci;
            float4 v = cur[d];
            float ma = m + v.x;
            float mo = fmaxf(ma, v.y);
            c = expf(ma - mo) * c + expf(v.y - mo) * v.z;
            m = mo;
        }
        #pragma unroll
        for (int d = 0; d < 16; ++d) cur[d] = nxt[d];
    }
}

// ---------------- scan phase C: replay chunks, emit h (fp16) ----------------
__global__ __launch_bounds__(256) void scan_c(const float* __restrict__ gates,
                                              const float2* __restrict__ c2,
                                              f16* __restrict__ h) {
    int w = blockIdx.x * 4 + (threadIdx.x >> 6);
    int lane = threadIdx.x & 63;
    int b = w >> 8, k = w & (NCHUNK - 1);
    int t0 = k * CLEN;
    float2 ci = c2[(size_t)(b * NCHUNK + k) * 64 + lane];
    float m = ci.x, c = ci.y;
    const float* gp = gates + ((size_t)(b * SS + t0)) * GLD + lane;
    f16* hp = h + ((size_t)(b * SS + t0)) * NN + lane;
    for (int t = 0; t < CLEN; ++t) {
        float li = gp[0], lf = gp[64], z = gp[128], o = gp[192];
        gp += GLD;
        float ma = m + lf;
        float mn = fmaxf(ma, li);
        c = expf(ma - mn) * c + expf(li - mn) * z;
        m = mn;
        *hp = (f16)(o * tanhf(c));
        hp += NN;
    }
}

// ---------------- output projection: h(32768x64) * Wpf^T(1024x64) + bp -> out ----------------
__global__ __launch_bounds__(256) void out_gemm(const f16* __restrict__ h,
                                                const f16* __restrict__ Wpf,
                                                const float* __restrict__ bp,
                                                float* __restrict__ out) {
    int tid = threadIdx.x, wid = tid >> 6, lane = tid & 63;
    int r0 = (blockIdx.x >> 1) * 32;
    int c0 = (blockIdx.x & 1) * 512 + wid * 128;
    int lrow = lane & 15, lk = (lane >> 4) * 8;

    f32x4 acc[2][8] = {};
    #pragma unroll
    for (int ks = 0; ks < 2; ++ks) {
        int kk = ks * 32;
        f16x8 a[2], bfr[8];
        #pragma unroll
        for (int mf = 0; mf < 2; ++mf)
            a[mf] = *reinterpret_cast<const f16x8*>(h + (size_t)(r0 + mf * 16 + lrow) * NN + kk + lk);
        #pragma unroll
        for (int nf = 0; nf < 8; ++nf)
            bfr[nf] = *reinterpret_cast<const f16x8*>(Wpf + (size_t)(c0 + nf * 16 + lrow) * NN + kk + lk);
        #pragma unroll
        for (int mf = 0; mf < 2; ++mf)
            #pragma unroll
            for (int nf = 0; nf < 8; ++nf)
                acc[mf][nf] = __builtin_amdgcn_mfma_f32_16x16x32_f16(a[mf], bfr[nf], acc[mf][nf], 0, 0, 0);
    }
    int rb = (lane >> 4) * 4;
    #pragma unroll
    for (int nf = 0; nf < 8; ++nf) {
        int col = c0 + nf * 16 + (lane & 15);
        float bias = bp[col];
        #pragma unroll
        for (int mf = 0; mf < 2; ++mf) {
            #pragma unroll
            for (int r = 0; r < 4; ++r) {
                int row = r0 + mf * 16 + rb + r;
                out[(size_t)row * DD + col] = acc[mf][nf][r] + bias;
            }
        }
    }
}

extern "C" void kernel_launch(void* const* d_in, const int* in_sizes, int n_in,
                              void* d_out, int out_size, void* d_ws, size_t ws_size,
                              hipStream_t stream) {
    const float* x    = (const float*)d_in[0];
    const float* ln_w = (const float*)d_in[1];
    const float* ln_b = (const float*)d_in[2];
    const float* Wi   = (const float*)d_in[3];
    const float* bi   = (const float*)d_in[4];
    const float* Wf   = (const float*)d_in[5];
    const float* bfv  = (const float*)d_in[6];
    const float* Wz   = (const float*)d_in[7];
    const float* bz   = (const float*)d_in[8];
    const float* Wo   = (const float*)d_in[9];
    const float* bo   = (const float*)d_in[10];
    const float* Wp   = (const float*)d_in[11];
    const float* bp   = (const float*)d_in[12];
    float* out = (float*)d_out;

    // gates fp32 [32768][256] at d_out floats [0, 8.39M)  (33.5 MB; dead before out_gemm)
    float* gates = (float*)d_out;
    // chunk summaries in dead d_out space (float offset 9M, 16B aligned)
    float4* s4 = (float4*)((float*)d_out + 9 * 1024 * 1024);
    float2* c2 = (float2*)((float*)d_out + 10 * 1024 * 1024);

    // Small scratch in ws (~4.9 MB)
    char* w = (char*)d_ws;
    f16* h    = (f16*)w; w += (size_t)ROWS * NN * 2;       // 4,194,304
    f16* Wpk  = (f16*)w; w += 32 * 8192 * 2;               // 524,288 (packed fp16 sub-slices)
    f16* Wpf  = (f16*)w; w += 1024 * 64 * 2;               // 131,072
    float* ball   = (float*)w;    w += 256 * 4;            // 1,024
    float* e_all  = (float*)w;    w += 256 * 4;            // 1,024

    prep_all<<<448, 256, 0, stream>>>(Wi, bi, Wf, bfv, Wz, bz, Wo, bo, Wp,
                                      ln_w, ln_b, Wpk, Wpf, ball, e_all);
    gate_gemm<<<ROWS / 128, 512, 0, stream>>>(x, Wpk, ball, e_all, gates, s4);
    scan_b<<<BB, 64, 0, stream>>>(s4, c2);
    scan_c<<<(BB * NCHUNK) / 4, 256, 0, stream>>>(gates, c2, h);
    out_gemm<<<(ROWS / 32) * 2, 256, 0, stream>>>(h, Wpf, bp, out);
}